// Round 23
// baseline (1090.230 us; speedup 1.0000x reference)
//
#include <hip/hip_runtime.h>

#define S 2048
#define DD 64
#define NH 32           // B*H
#define NW 8            // waves per block
#define KSLICE 256      // k columns per wave
#define NT 16           // 16-wide k tiles per wave

typedef float f32x4 __attribute__((ext_vector_type(4)));
typedef float f32x2 __attribute__((ext_vector_type(2)));
typedef unsigned int u32x4 __attribute__((ext_vector_type(4)));
typedef short bf16x8 __attribute__((ext_vector_type(8)));
typedef _Float16 f16x4 __attribute__((ext_vector_type(4)));
typedef _Float16 f16x8 __attribute__((ext_vector_type(8)));

__device__ inline unsigned int packsplit(float x){
  unsigned int u = __float_as_uint(x);
  unsigned int h = u >> 16;
  float rem = x - __uint_as_float(h << 16);
  unsigned int l = __float_as_uint(rem) >> 16;
  return (h << 16) | l;
}
__device__ inline void split2(float x, short &hi, short &lo){
  unsigned int p = packsplit(x);
  hi = (short)(p >> 16); lo = (short)(p & 0xFFFFu);
}
__device__ inline f32x4 ntload4(const float* p){
  return __builtin_nontemporal_load(reinterpret_cast<const f32x4*>(p));
}
// wave-local LDS ordering fence
__device__ inline void wave_lds_fence(){
  asm volatile("s_waitcnt lgkmcnt(0)" ::: "memory");
  __builtin_amdgcn_sched_barrier(0);
}

// ---- pre-pack kernels ----
__global__ void pack_k_kernel(const float* __restrict__ in, unsigned int* __restrict__ out, int n4){
  int i = blockIdx.x * 256 + threadIdx.x;
  if (i < n4){
    f32x4 x = ntload4(in + 4*(size_t)i);
    u32x4 p;
    p.x = packsplit(x.x); p.y = packsplit(x.y);
    p.z = packsplit(x.z); p.w = packsplit(x.w);
    reinterpret_cast<u32x4*>(out)[i] = p;
  }
}

__global__ void pack_vt_kernel(const float* __restrict__ v, unsigned int* __restrict__ vt){
  const int head = blockIdx.x >> 5;
  const int s0   = (blockIdx.x & 31) * 64;
  const float* vh = v + (size_t)head * S * DD;
  unsigned int* vth = vt + (size_t)head * DD * S;
  __shared__ unsigned int tile[64][65];
  const int tid = threadIdx.x;
  for (int i = tid; i < 64*64; i += 256){
    int s = i >> 6, d = i & 63;
    tile[d][s] = packsplit(__builtin_nontemporal_load(&vh[(size_t)(s0 + s) * DD + d]));
  }
  __syncthreads();
  for (int i = tid; i < 64*64; i += 256){
    int d = i >> 6, s = i & 63;
    vth[(size_t)d * S + s0 + s] = tile[d][s];
  }
}

// ==== K1: QK^T -> fp16 scores in the first 4KB of each row's 8KB weight
// slot. BLOCK-level transpose: wave w then stores rows 2w,2w+1 COMPLETELY,
// address-sequential (K2's clean-write shape: full region, one writer,
// in-order) - tests the write-combining/sequencing theory. ====
template<bool PACKED>
__global__ __launch_bounds__(512, 4)
void qk_scores_kernel(const float* __restrict__ q, const float* __restrict__ k,
                      const unsigned int* __restrict__ kp, float* __restrict__ sc)
{
  const int head = blockIdx.y;
  const int q0   = blockIdx.x * 16;
  const int tid  = threadIdx.x;
  const int wid  = tid >> 6;
  const int lane = tid & 63;
  const int lr   = lane & 15;
  const int lg   = lane >> 4;

  const float* qh = q + (size_t)head * S * DD;
  const float* kh = k + (size_t)head * S * DD;
  const unsigned int* kph = kp + (size_t)head * S * DD;
  float* sh = sc + (size_t)head * S * S;

  // block-level fp16 transpose buffer; row stride 2088 halfs (4176B) spreads
  // write banks: lr*1044%32 cycles 8 banks, +lg*2 -> 32 banks, 2 lanes/bank
  __shared__ unsigned short st16[16][2088];   // 66.8 KB

  // Q fragments, pre-scaled by 1/sqrt(64)
  bf16x8 qhi[2], qlo[2];
  {
    const float* qrow = qh + (size_t)(q0 + lr) * DD;
#pragma unroll
    for (int ks = 0; ks < 2; ++ks){
      float4 a = *reinterpret_cast<const float4*>(qrow + ks*32 + lg*8);
      float4 b = *reinterpret_cast<const float4*>(qrow + ks*32 + lg*8 + 4);
      float f[8] = {a.x,a.y,a.z,a.w,b.x,b.y,b.z,b.w};
#pragma unroll
      for (int j = 0; j < 8; ++j){
        short h, l2; split2(f[j] * 0.125f, h, l2);
        qhi[ks][j] = h; qlo[ks][j] = l2;
      }
    }
  }

  const int kw0 = wid * KSLICE;
  f32x4 acc[NT];
#pragma unroll
  for (int t = 0; t < NT; ++t) acc[t] = (f32x4){0.f,0.f,0.f,0.f};

#pragma unroll 2
  for (int t = 0; t < NT; ++t){
    const int kbase = kw0 + 16*t;
    bf16x8 khi[2], klo[2];
    if constexpr (PACKED){
      const unsigned int* kr = kph + (size_t)(kbase + lr) * DD;
#pragma unroll
      for (int ks = 0; ks < 2; ++ks){
        uint4 pa = *reinterpret_cast<const uint4*>(kr + ks*32 + lg*8);
        uint4 pb = *reinterpret_cast<const uint4*>(kr + ks*32 + lg*8 + 4);
        unsigned int pw[8] = {pa.x,pa.y,pa.z,pa.w,pb.x,pb.y,pb.z,pb.w};
#pragma unroll
        for (int j = 0; j < 8; ++j){
          khi[ks][j] = (short)(pw[j] >> 16);
          klo[ks][j] = (short)(pw[j] & 0xFFFFu);
        }
      }
    } else {
      const float* krow = kh + (size_t)(kbase + lr) * DD;
#pragma unroll
      for (int ks = 0; ks < 2; ++ks){
        float4 a = *reinterpret_cast<const float4*>(krow + ks*32 + lg*8);
        float4 b = *reinterpret_cast<const float4*>(krow + ks*32 + lg*8 + 4);
        float f[8] = {a.x,a.y,a.z,a.w,b.x,b.y,b.z,b.w};
#pragma unroll
        for (int j = 0; j < 8; ++j){
          short h, l2; split2(f[j], h, l2);
          khi[ks][j] = h; klo[ks][j] = l2;
        }
      }
    }
#pragma unroll
    for (int ks = 0; ks < 2; ++ks){
      acc[t] = __builtin_amdgcn_mfma_f32_16x16x32_bf16(klo[ks], qhi[ks], acc[t], 0,0,0);
      acc[t] = __builtin_amdgcn_mfma_f32_16x16x32_bf16(khi[ks], qlo[ks], acc[t], 0,0,0);
      acc[t] = __builtin_amdgcn_mfma_f32_16x16x32_bf16(khi[ks], qhi[ks], acc[t], 0,0,0);
    }
  }

  // ---- block transpose: lane's frag row is lr, cols kw0+16t+lg*4
#pragma unroll
  for (int t = 0; t < NT; ++t){
    f16x4 hv;
#pragma unroll
    for (int r = 0; r < 4; ++r) hv[r] = (_Float16)acc[t][r];
    *reinterpret_cast<f16x4*>(&st16[lr][kw0 + 16*t + lg*4]) = hv;
  }
  __syncthreads();

  // ---- wave w stores rows 2w, 2w+1 completely: 4 x 1KB sequential per row
#pragma unroll
  for (int rr = 0; rr < 2; ++rr){
    const int row = 2*wid + rr;
    _Float16* dst = reinterpret_cast<_Float16*>(sh + (size_t)(q0 + row) * S);
#pragma unroll
    for (int c = 0; c < 4; ++c){
      f16x8 hv = *reinterpret_cast<const f16x8*>(&st16[row][c*512 + lane*8]);
      *reinterpret_cast<f16x8*>(dst + c*512 + lane*8) = hv;
    }
  }
}

// ==== K2: row softmax of (fp16 scores + bias - 0.5*g^2); in-place. ====
__global__ __launch_bounds__(256, 8)
void softmax_row_kernel(const float* __restrict__ bias, const float* __restrict__ gb,
                        float* __restrict__ w)
{
  const int bid  = (NH * S - 1) - (int)blockIdx.x;   // reverse: catch K1's L3-warm tail
  const int head = bid >> 11;
  const int row  = bid & (S - 1);
  const size_t ro = ((size_t)head * S + row) * S;
  const int tid  = threadIdx.x;
  const int wid  = tid >> 6;
  const int lane = tid & 63;
  const int c0   = tid * 8;

  const _Float16* sp = reinterpret_cast<const _Float16*>(w + ro);
  f16x8 sv = *reinterpret_cast<const f16x8*>(sp + c0);
  f32x4 b0 = ntload4(bias + ro + c0);
  f32x4 b1 = ntload4(bias + ro + c0 + 4);
  f32x4 g0 = ntload4(gb + ro + c0);
  f32x4 g1 = ntload4(gb + ro + c0 + 4);

  float x[8];
#pragma unroll
  for (int j = 0; j < 4; ++j){
    x[j]   = (float)sv[j]   + b0[j] - 0.5f * g0[j] * g0[j];
    x[4+j] = (float)sv[4+j] + b1[j] - 0.5f * g1[j] * g1[j];
  }

  __shared__ float redm[4], reds[4];

  float m = x[0];
#pragma unroll
  for (int j = 1; j < 8; ++j) m = fmaxf(m, x[j]);
#pragma unroll
  for (int off = 1; off < 64; off <<= 1) m = fmaxf(m, __shfl_xor(m, off, 64));
  if (lane == 0) redm[wid] = m;
  __syncthreads();
  m = fmaxf(fmaxf(redm[0], redm[1]), fmaxf(redm[2], redm[3]));

  float e[8], s = 0.f;
#pragma unroll
  for (int j = 0; j < 8; ++j){ e[j] = __expf(x[j] - m); s += e[j]; }
#pragma unroll
  for (int off = 1; off < 64; off <<= 1) s += __shfl_xor(s, off, 64);
  if (lane == 0) reds[wid] = s;
  __syncthreads();
  const float inv = 1.0f / (reds[0] + reds[1] + reds[2] + reds[3]);

  f32x4 w0, w1;
#pragma unroll
  for (int j = 0; j < 4; ++j){ w0[j] = e[j] * inv; w1[j] = e[4+j] * inv; }
  *reinterpret_cast<f32x4*>(w + ro + c0)     = w0;
  *reinterpret_cast<f32x4*>(w + ro + c0 + 4) = w1;
}

// ==== K3: out = W x V, wave-independent, 4x64-col chunks with 2-deep LDS
// rotation (chunk c+1 loads fly during chunk c's MFMA). ====
template<bool PACKED>
__global__ __launch_bounds__(512, 4)
void pv_kernel(const float* __restrict__ w, const float* __restrict__ v,
               const unsigned int* __restrict__ vtp, float* __restrict__ out)
{
  const int head = blockIdx.y;
  const int q0   = blockIdx.x * 16;
  const int tid  = threadIdx.x;
  const int wid  = tid >> 6;
  const int lane = tid & 63;
  const int lr   = lane & 15;
  const int lg   = lane >> 4;

  const float* wh = w + (size_t)head * S * S;
  const float* vh = v + (size_t)head * S * DD;
  const unsigned int* vtph = vtp + (size_t)head * DD * S;
  float* oh = out + (size_t)head * S * DD;

  __shared__ float buf[NW][2][16][68];               // 69.6 KB, 2-deep rotation

  const int kw0 = wid * KSLICE;
  const int prow = lane >> 5;                        // fill: 2 rows per instr
  const int pcol = (lane & 31) * 2;

  f32x4 oacc[4];
#pragma unroll
  for (int n = 0; n < 4; ++n) oacc[n] = (f32x4){0.f,0.f,0.f,0.f};

  f32x2 pre[8];
#pragma unroll
  for (int i = 0; i < 8; ++i)
    pre[i] = *reinterpret_cast<const f32x2*>(
        wh + (size_t)(q0 + 2*i + prow) * S + kw0 + pcol);

#pragma unroll 1
  for (int c = 0; c < 4; ++c){
    const int b = c & 1;
#pragma unroll
    for (int i = 0; i < 8; ++i)
      *reinterpret_cast<f32x2*>(&buf[wid][b][2*i + prow][pcol]) = pre[i];
    if (c < 3){
#pragma unroll
      for (int i = 0; i < 8; ++i)
        pre[i] = *reinterpret_cast<const f32x2*>(
            wh + (size_t)(q0 + 2*i + prow) * S + kw0 + 64*(c+1) + pcol);
    }
    wave_lds_fence();

    const int kc = kw0 + 64*c;
#pragma unroll
    for (int ks = 0; ks < 2; ++ks){
      f32x4 wa = *reinterpret_cast<const f32x4*>(&buf[wid][b][lr][32*ks + lg*8]);
      f32x4 wb = *reinterpret_cast<const f32x4*>(&buf[wid][b][lr][32*ks + lg*8 + 4]);
      float f[8] = {wa[0],wa[1],wa[2],wa[3],wb[0],wb[1],wb[2],wb[3]};
      bf16x8 ahi, alo;
#pragma unroll
      for (int j = 0; j < 8; ++j){
        short hh, ll; split2(f[j], hh, ll);
        ahi[j] = hh; alo[j] = ll;
      }
#pragma unroll
      for (int n = 0; n < 4; ++n){
        bf16x8 bhi, blo;
        if constexpr (PACKED){
          const unsigned int* vrow = vtph + (size_t)(16*n + lr) * S + kc + 32*ks + lg*8;
          uint4 pv0 = *reinterpret_cast<const uint4*>(vrow);
          uint4 pv1 = *reinterpret_cast<const uint4*>(vrow + 4);
          unsigned int pw[8] = {pv0.x,pv0.y,pv0.z,pv0.w,pv1.x,pv1.y,pv1.z,pv1.w};
#pragma unroll
          for (int j = 0; j < 8; ++j){
            bhi[j] = (short)(pw[j] >> 16);
            blo[j] = (short)(pw[j] & 0xFFFFu);
          }
        } else {
#pragma unroll
          for (int j = 0; j < 8; ++j){
            float x = vh[(size_t)(kc + 32*ks + lg*8 + j) * DD + 16*n + lr];
            short hh, ll; split2(x, hh, ll);
            bhi[j] = hh; blo[j] = ll;
          }
        }
        oacc[n] = __builtin_amdgcn_mfma_f32_16x16x32_bf16(alo, bhi, oacc[n], 0,0,0);
        oacc[n] = __builtin_amdgcn_mfma_f32_16x16x32_bf16(ahi, blo, oacc[n], 0,0,0);
        oacc[n] = __builtin_amdgcn_mfma_f32_16x16x32_bf16(ahi, bhi, oacc[n], 0,0,0);
      }
    }
  }

  // cross-wave reduction of out partials (alias buf)
  float (*sO)[16][68] = reinterpret_cast<float(*)[16][68]>(&buf[0][0][0][0]);
  __syncthreads();
#pragma unroll
  for (int n = 0; n < 4; ++n)
#pragma unroll
    for (int r = 0; r < 4; ++r)
      sO[wid][lg*4 + r][16*n + lr] = oacc[n][r];
  __syncthreads();
#pragma unroll
  for (int i = tid; i < 16*64; i += 512){
    int row = i >> 6, d = i & 63;
    float ssum = 0.f;
#pragma unroll
    for (int wv = 0; wv < NW; ++wv) ssum += sO[wv][row][d];
    __builtin_nontemporal_store(ssum, &oh[(size_t)(q0 + row) * DD + d]);
  }
}

extern "C" void kernel_launch(void* const* d_in, const int* in_sizes, int n_in,
                              void* d_out, int out_size, void* d_ws, size_t ws_size,
                              hipStream_t stream) {
  const float* q    = (const float*)d_in[0];
  const float* k    = (const float*)d_in[1];
  const float* v    = (const float*)d_in[2];
  const float* bias = (const float*)d_in[3];
  const float* gb   = (const float*)d_in[4];
  float* out  = (float*)d_out;
  float* wout = (float*)d_out + (size_t)NH * S * DD;

  const size_t nelem = (size_t)NH * S * DD;       // 4.19M
  const size_t need  = 2 * nelem * sizeof(unsigned int);

  dim3 gridT(S / 16, NH);
  dim3 block512(512);

  if (ws_size >= need){
    unsigned int* kp  = (unsigned int*)d_ws;
    unsigned int* vtp = kp + nelem;
    int n4 = (int)(nelem / 4);
    pack_k_kernel<<<(n4 + 255) / 256, 256, 0, stream>>>(k, kp, n4);
    pack_vt_kernel<<<NH * 32, 256, 0, stream>>>(v, vtp);
    qk_scores_kernel<true ><<<gridT, block512, 0, stream>>>(q, k, kp, wout);
    softmax_row_kernel<<<NH * S, 256, 0, stream>>>(bias, gb, wout);
    pv_kernel<true ><<<gridT, block512, 0, stream>>>(wout, v, vtp, out);
  } else {
    qk_scores_kernel<false><<<gridT, block512, 0, stream>>>(q, k, nullptr, wout);
    softmax_row_kernel<<<NH * S, 256, 0, stream>>>(bias, gb, wout);
    pv_kernel<false><<<gridT, block512, 0, stream>>>(wout, v, nullptr, out);
  }
}